// Round 6
// baseline (219.901 us; speedup 1.0000x reference)
//
#include <hip/hip_runtime.h>

// LocalitySelfAttention: B=2, N=4096, DIM=512, H=8, d=64 (INNER=512)
// bf16 MFMA, fp32 accumulate. Head (b,h) = contiguous (4096x64) tile at
// offset (b*8+h)<<18 of the (8192x512) activation matrices (raw-reshape view).

typedef __bf16 bf16;
typedef __bf16 bf16x8 __attribute__((ext_vector_type(8)));
typedef __bf16 bf16x4 __attribute__((ext_vector_type(4)));
typedef __bf16 bf16x2 __attribute__((ext_vector_type(2)));
typedef float  f32x4  __attribute__((ext_vector_type(4)));
typedef float  f32x16 __attribute__((ext_vector_type(16)));
typedef unsigned u32x4 __attribute__((ext_vector_type(4)));

#define MFMA_BF16(a, b, c)   __builtin_amdgcn_mfma_f32_16x16x32_bf16((a), (b), (c), 0, 0, 0)
#define MFMA32_BF16(a, b, c) __builtin_amdgcn_mfma_f32_32x32x16_bf16((a), (b), (c), 0, 0, 0)

__device__ __forceinline__ void gld_lds16(void* lds, const void* g) {
  __builtin_amdgcn_global_load_lds(
      (const __attribute__((address_space(1))) void*)g,
      (__attribute__((address_space(3))) void*)lds, 16, 0, 0);
}

// pack two f32 -> one u32 of 2 bf16
__device__ __forceinline__ unsigned pkbf(float a, float b) {
  bf16x2 t; t[0] = (bf16)a; t[1] = (bf16)b;
  return __builtin_bit_cast(unsigned, t);
}

// ---------------- converters ----------------

__global__ void cast4_kernel(const float* __restrict__ in, bf16* __restrict__ out, int n4) {
  int i = blockIdx.x * 256 + threadIdx.x;
  if (i >= n4) return;
  float4 v = ((const float4*)in)[i];
  bf16x4 o;
  o[0] = (bf16)v.x; o[1] = (bf16)v.y; o[2] = (bf16)v.z; o[3] = (bf16)v.w;
  *(bf16x4*)(out + 4 * i) = o;
}

// out (C x 512) = in (512 x C)^T, f32 -> bf16, LDS-tiled
__global__ void wtrans_kernel(const float* __restrict__ in, bf16* __restrict__ out, int C) {
  __shared__ float tile[64 * 65];
  const int t = threadIdx.x;
  const int c0 = blockIdx.x * 64, r0 = blockIdx.y * 64;
#pragma unroll
  for (int p = 0; p < 16; p++) {
    int idx = p * 256 + t, r = idx >> 6, c = idx & 63;
    tile[r * 65 + c] = in[(r0 + r) * C + c0 + c];
  }
  __syncthreads();
#pragma unroll
  for (int p = 0; p < 16; p++) {
    int idx = p * 256 + t, c = idx >> 6, r = idx & 63;
    out[(size_t)(c0 + c) * 512 + r0 + r] = (bf16)tile[r * 65 + c];
  }
}

// per-head (4096x64) -> (64x4096), LDS-tiled. grid (64 n-tiles, 16 heads)
__global__ void vtrans_kernel(const bf16* __restrict__ V, bf16* __restrict__ Vt) {
  __shared__ bf16 tile[64 * 65];
  const int t = threadIdx.x;
  const size_t base = (size_t)blockIdx.y << 18;
  const int n0 = blockIdx.x * 64;
#pragma unroll
  for (int p = 0; p < 16; p++) {
    int idx = p * 256 + t, r = idx >> 6, c = idx & 63;
    tile[r * 65 + c] = V[base + (size_t)(n0 + r) * 64 + c];
  }
  __syncthreads();
#pragma unroll
  for (int p = 0; p < 16; p++) {
    int idx = p * 256 + t, d = idx >> 6, n = idx & 63;
    Vt[base + (size_t)d * 4096 + n0 + n] = tile[n * 65 + d];
  }
}

// ---------------- GEMM: C(M x *) = A(Mx512) * Bt(*x512)^T ----------------

template<int EPI, int WNT>
__global__ __launch_bounds__(256) void gemm_bt(
    const bf16* __restrict__ A, const bf16* __restrict__ Bt,
    bf16* __restrict__ oQ, bf16* __restrict__ oK, bf16* __restrict__ oV,
    float* __restrict__ oC, const float* __restrict__ bias,
    const float* __restrict__ temp)
{
  __shared__ bf16 As[128 * 32];
  __shared__ bf16 Bs[WNT * 32 * 32];

  const int t    = threadIdx.x;
  const int lane = t & 63;
  const int w    = t >> 6;
  const int mm   = lane & 15;
  const int q    = lane >> 4;
  const int wm   = w >> 1, wn = w & 1;
  const int m0   = blockIdx.y * 128;
  const int n0   = blockIdx.x * (WNT * 32);

  const int srow = t >> 2, sch = t & 3;
  const int gch  = sch ^ ((srow >> 1) & 3);
  const bf16* Ab = A  + (m0 + srow) * 512 + gch * 8;
  const bf16* Bb = Bt + (n0 + srow) * 512 + gch * 8;
  bf16* Asl = As + t * 8;
  bf16* Bsl = Bs + t * 8;

  const int fslot = (q ^ ((mm >> 1) & 3)) * 8;

  const f32x4 zero4 = {0.f, 0.f, 0.f, 0.f};
  f32x4 acc[4][WNT];
#pragma unroll
  for (int i = 0; i < 4; i++)
#pragma unroll
    for (int j = 0; j < WNT; j++) acc[i][j] = zero4;

  for (int k0 = 0; k0 < 512; k0 += 32) {
    __syncthreads();
    gld_lds16(Asl,        Ab + k0);
    gld_lds16(Asl + 2048, Ab + 64 * 512 + k0);
    gld_lds16(Bsl,        Bb + k0);
    if (WNT == 4) gld_lds16(Bsl + 2048, Bb + 64 * 512 + k0);
    __syncthreads();

    bf16x8 af[4], bfv[WNT];
#pragma unroll
    for (int i = 0; i < 4; i++)
      af[i] = *(const bf16x8*)(As + (wm * 64 + i * 16 + mm) * 32 + fslot);
#pragma unroll
    for (int j = 0; j < WNT; j++)
      bfv[j] = *(const bf16x8*)(Bs + (wn * (WNT * 16) + j * 16 + mm) * 32 + fslot);

#pragma unroll
    for (int i = 0; i < 4; i++)
#pragma unroll
      for (int j = 0; j < WNT; j++)
        acc[i][j] = MFMA_BF16(af[i], bfv[j], acc[i][j]);
  }

  if (EPI == 0) {
    // fold exp(temperature) AND log2(e) into Q so attention uses raw exp2
    const float scale = __expf(temp[0]) * 1.44269504088896f;
#pragma unroll
    for (int i = 0; i < 4; i++) {
      const int row = m0 + wm * 64 + i * 16 + q * 4;
#pragma unroll
      for (int j = 0; j < WNT; j++) {
        const int col = n0 + wn * (WNT * 16) + j * 16 + mm;
        bf16* dst; int c2; float s;
        if (col < 512)       { dst = oQ; c2 = col;        s = scale; }
        else if (col < 1024) { dst = oK; c2 = col - 512;  s = 1.0f;  }
        else                 { dst = oV; c2 = col - 1024; s = 1.0f;  }
#pragma unroll
        for (int r = 0; r < 4; r++)
          dst[(size_t)(row + r) * 512 + c2] = (bf16)(acc[i][j][r] * s);
      }
    }
  } else {
#pragma unroll
    for (int i = 0; i < 4; i++) {
      const int row = m0 + wm * 64 + i * 16 + q * 4;
#pragma unroll
      for (int j = 0; j < WNT; j++) {
        const int col = n0 + wn * (WNT * 16) + j * 16 + mm;
        const float b = bias[col];
#pragma unroll
        for (int r = 0; r < 4; r++)
          oC[(size_t)(row + r) * 512 + col] = acc[i][j][r] + b;
      }
    }
  }
}

// ---------------- flash attention v9: fence-free loop body + desync ----------------
// 4 waves x 32 Q-rows = 128-row block; KV tile 64; grid (32, 16, SPLIT).
// QK as mfma_32x32x16(A=K, B=Q): C col (lane&31) = Q-row == the A-frag row
// index PV needs -> P never touches LDS. kv redistribution across lane halves:
// one ds_bpermute (lane^32) + selects per fragment pair. p = exp2(s) raw.
// K/V double-buffered in LDS; unconditional wrapped prefetch + counted
// s_waitcnt vmcnt(4) + raw s_barrier keep prefetch in flight across barriers.
//
// v8 post-mortem: doubling occupancy (2->4 waves/SIMD) changed nothing; no
// pipe >45% busy -> per-wave critical path is the limiter, and the loop body
// was chopped into ~5 scheduler regions by setprio pairs + the per-kt diag
// branch + the prefetch branch. v9: (1) no setprio, (2) diag mask hoisted to
// one rare uniform branch after both QK clusters, (3) branchless wrapped
// prefetch, (4) per-block kv-tile ROTATION (sum is commutative; no online
// max) so co-resident blocks desynchronize and pipes interleave across waves.

template<int SPLIT>
__global__ __launch_bounds__(256, 4) void attn_kernel(
    const bf16* __restrict__ Q, const bf16* __restrict__ Kb,
    const bf16* __restrict__ Vt, bf16* __restrict__ O,
    float* __restrict__ Opart, float* __restrict__ Lpart)
{
  __shared__ bf16 Ks[2][64 * 64];   // [buf][kv][d], chunk-swizzle key = kv&7
  __shared__ bf16 Vs[2][64 * 64];   // [buf][d][kv], chunk-swizzle key = d&7
  __shared__ float rsum[4][32];     // SPLIT==1 epilogue only

  const int t    = threadIdx.x;
  const int lane = t & 63;
  const int w    = t >> 6;
  const int c32  = lane & 31;
  const int h    = lane >> 5;
  const int pxa  = (lane ^ 32) << 2;   // ds_bpermute byte index of partner lane
  const int bh   = blockIdx.y;
  const int q0   = blockIdx.x * 128;
  const int z    = blockIdx.z;
  const size_t hb = (size_t)bh << 18;
  const bf16* Qh = Q  + hb;
  const bf16* Kh = Kb + hb;
  const bf16* Vh = Vt + hb;
  const int q0w  = q0 + w * 32;     // this wave's first Q row (32-aligned)

  // kv tile range for this split part (tiles of 64); tn is a power of 2
  int tlo, tn;
  if (SPLIT == 1)      { tlo = 0;      tn = 64; }
  else                 { tlo = z * 32; tn = 32; }
  const int tmask = tn - 1;
  // per-block rotation of the kv iteration order (desyncs co-resident blocks)
  const int rot = (blockIdx.x * 5 + bh * 11 + z * 16) & tmask;

  // Q B-frags (32x32x16): B[k][n], n = lane&31 = qrow, k = h*8+e per k-slot.
  bf16x8 qf[4];
#pragma unroll
  for (int s = 0; s < 4; s++)
    qf[s] = *(const bf16x8*)(Qh + (size_t)(q0w + c32) * 64 + s * 16 + h * 8);

  f32x16 o[2];              // o[dt]: C col = d (dt*32+c32), row = qrow via regs
#pragma unroll
  for (int dt = 0; dt < 2; dt++)
#pragma unroll
    for (int r = 0; r < 16; r++) o[dt][r] = 0.f;
  float lacc = 0.f;         // per-lane partial row sum, qrow = q0w + c32

  const int r0 = t >> 3, c0 = t & 7;
  const int g0 = c0 ^ (r0 & 7);
  const bf16* Kg = Kh + (size_t)r0 * 64 + g0 * 8;     // + kv*64 per tile
  const bf16* Vg = Vh + (size_t)r0 * 4096 + g0 * 8;   // + kv    per tile

  // which kv half-tile (kt) holds this wave's diagonal, and its tile base
  const int dbase = q0w & ~63;
  const int kthalf = (q0w >> 5) & 1;

  // prologue: issue rotated tile 0 into buf 0
  {
    const int kv0 = (tlo + rot) * 64;
    gld_lds16(&Ks[0][t * 8],        Kg + (size_t)kv0 * 64);
    gld_lds16(&Ks[0][t * 8] + 2048, Kg + (size_t)(kv0 + 32) * 64);
    gld_lds16(&Vs[0][t * 8],        Vg + kv0);
    gld_lds16(&Vs[0][t * 8] + 2048, Vg + (size_t)32 * 4096 + kv0);
  }

  for (int it = 0; it < tn; it++) {
    const int cur = it & 1;
    // branchless wrapped prefetch: last iter re-fetches the start tile
    // (harmless) so the loop body has no control flow at all.
    {
      const int kvn = (tlo + ((it + 1 + rot) & tmask)) * 64;
      bf16* Kn = &Ks[cur ^ 1][t * 8];
      bf16* Vn = &Vs[cur ^ 1][t * 8];
      gld_lds16(Kn,        Kg + (size_t)kvn * 64);
      gld_lds16(Kn + 2048, Kg + (size_t)(kvn + 32) * 64);
      gld_lds16(Vn,        Vg + kvn);
      gld_lds16(Vn + 2048, Vg + (size_t)32 * 4096 + kvn);
    }
    // counted wait: the 4 just-issued loads stay in flight; tile-it's landed.
    __asm__ volatile("s_waitcnt vmcnt(4)" ::: "memory");
    __builtin_amdgcn_s_barrier();
    __asm__ volatile("" ::: "memory");

    const int kv0 = (tlo + ((it + rot) & tmask)) * 64;
    const bool diag = (kv0 == dbase);
    const bf16* Kc = Ks[cur];
    const bf16* Vc = Vs[cur];

    // ---- QK for both kv halves (one scheduling region) ----
    f32x16 sv0, sv1;
#pragma unroll
    for (int r = 0; r < 16; r++) { sv0[r] = 0.f; sv1[r] = 0.f; }
    {
      bf16x8 kf[4];
#pragma unroll
      for (int s = 0; s < 4; s++)
        kf[s] = *(const bf16x8*)(Kc + c32 * 64 + (((s << 1) | h) ^ (c32 & 7)) * 8);
#pragma unroll
      for (int s = 0; s < 4; s++)
        sv0 = MFMA32_BF16(kf[s], qf[s], sv0);
    }
    {
      const int kr = 32 + c32;
      bf16x8 kf[4];
#pragma unroll
      for (int s = 0; s < 4; s++)
        kf[s] = *(const bf16x8*)(Kc + kr * 64 + (((s << 1) | h) ^ (kr & 7)) * 8);
#pragma unroll
      for (int s = 0; s < 4; s++)
        sv1 = MFMA32_BF16(kf[s], qf[s], sv1);
    }

    // ---- diagonal mask: one rare wave-uniform branch per iteration ----
    if (diag) {
      if (kthalf == 0) {
#pragma unroll
        for (int r = 0; r < 16; r++)
          if (c32 == ((r & 3) + ((r >> 2) << 3) + (h << 2))) sv0[r] = -1e30f;
      } else {
#pragma unroll
        for (int r = 0; r < 16; r++)
          if (c32 == ((r & 3) + ((r >> 2) << 3) + (h << 2))) sv1[r] = -1e30f;
      }
    }

    // ---- exp2 + row-sum + pack -> PV A-frags, both halves; then PV ----
    bf16x8 pa00, pa01, pa10, pa11;   // pa<kt><s2>
#pragma unroll
    for (int kt = 0; kt < 2; kt++) {
      float pp[16];
#pragma unroll
      for (int r = 0; r < 16; r++)
        pp[r] = __builtin_amdgcn_exp2f(kt ? sv1[r] : sv0[r]);
      float s8[8];
#pragma unroll
      for (int r = 0; r < 8; r++) s8[r] = pp[r] + pp[r + 8];
      float s4[4];
#pragma unroll
      for (int r = 0; r < 4; r++) s4[r] = s8[r] + s8[r + 4];
      lacc += (s4[0] + s4[1]) + (s4[2] + s4[3]);

      // Lane (c32,h) holds kv {4h+0..3, 8+4h+0..3} per 16-step; A-frag word j
      // needs k = 8h + {2j,2j+1}; the other half's words come from lane^32.
#pragma unroll
      for (int s2 = 0; s2 < 2; s2++) {
        const int b = s2 * 8;
        unsigned wa = pkbf(pp[b + 0], pp[b + 1]);
        unsigned wc = pkbf(pp[b + 2], pp[b + 3]);
        unsigned wb = pkbf(pp[b + 4], pp[b + 5]);
        unsigned wd = pkbf(pp[b + 6], pp[b + 7]);
        unsigned r1 = (unsigned)__builtin_amdgcn_ds_bpermute(pxa, (int)(h ? wa : wb));
        unsigned r2 = (unsigned)__builtin_amdgcn_ds_bpermute(pxa, (int)(h ? wc : wd));
        u32x4 wv;
        wv[0] = h ? r1 : wa;
        wv[1] = h ? r2 : wc;
        wv[2] = h ? wb : r1;
        wv[3] = h ? wd : r2;
        bf16x8 pa = __builtin_bit_cast(bf16x8, wv);
        if (kt == 0) { if (s2 == 0) pa00 = pa; else pa01 = pa; }
        else         { if (s2 == 0) pa10 = pa; else pa11 = pa; }
      }
    }

    // O += P V over both kv32 subtiles (4 kv16 k-steps)
#pragma unroll
    for (int kt = 0; kt < 2; kt++)
#pragma unroll
      for (int s2 = 0; s2 < 2; s2++) {
        const bf16x8 pa = kt ? (s2 ? pa11 : pa10) : (s2 ? pa01 : pa00);
        bf16x8 vf[2];
#pragma unroll
        for (int dt = 0; dt < 2; dt++) {
          const int d = dt * 32 + c32;
          vf[dt] = *(const bf16x8*)(Vc + d * 64 + (((((kt << 1) | s2) << 1) | h) ^ (d & 7)) * 8);
        }
#pragma unroll
        for (int dt = 0; dt < 2; dt++)
          o[dt] = MFMA32_BF16(pa, vf[dt], o[dt]);
      }

    __asm__ volatile("" ::: "memory");
    __builtin_amdgcn_s_barrier();   // all waves done reading buf[cur]
  }

  // combine per-lane partial row sums across lane halves (kv coverage is
  // complementary between lane l and l^32; qrow identical)
  const int pb = __builtin_amdgcn_ds_bpermute(pxa, __builtin_bit_cast(int, lacc));
  const float tot = lacc + __builtin_bit_cast(float, pb);

  if (SPLIT == 1) {
    bf16* Oh = O + hb;
    if (h == 0) rsum[w][c32] = tot;
    __asm__ volatile("s_waitcnt lgkmcnt(0)" ::: "memory");
#pragma unroll
    for (int r = 0; r < 16; r++) {
      const int row = (r & 3) + ((r >> 2) << 3) + (h << 2);
      const float rinv = 1.0f / rsum[w][row];
#pragma unroll
      for (int dt = 0; dt < 2; dt++)
        Oh[(size_t)(q0w + row) * 64 + dt * 32 + c32] = (bf16)(o[dt][r] * rinv);
    }
  } else {
    float* Op = Opart + ((size_t)z << 22) + hb;
    float* Lp = Lpart + (z << 16) + (bh << 12);
    if (h == 0) Lp[q0w + c32] = tot;
#pragma unroll
    for (int r = 0; r < 16; r++) {
      const int row = (r & 3) + ((r >> 2) << 3) + (h << 2);
#pragma unroll
      for (int dt = 0; dt < 2; dt++)
        Op[(size_t)(q0w + row) * 64 + dt * 32 + c32] = o[dt][r];
    }
  }
}

// merge kv-split partials: Ob = (sum_z Oz) / (sum_z lz)
template<int SPLIT>
__global__ void merge_kernel(const float* __restrict__ Op, const float* __restrict__ Lp,
                             bf16* __restrict__ Ob) {
  const int g = blockIdx.x * 256 + threadIdx.x;
  const int f = g * 4;
  const int row = f >> 6;
  float l = 0.f;
  float4 a = {0.f, 0.f, 0.f, 0.f};
#pragma unroll
  for (int zz = 0; zz < SPLIT; zz++) {
    l += Lp[(zz << 16) + row];
    const float4 b = *(const float4*)(Op + ((size_t)zz << 22) + f);
    a.x += b.x; a.y += b.y; a.z += b.z; a.w += b.w;
  }
  const float rinv = 1.0f / l;
  bf16x4 o;
  o[0] = (bf16)(a.x * rinv);
  o[1] = (bf16)(a.y * rinv);
  o[2] = (bf16)(a.z * rinv);
  o[3] = (bf16)(a.w * rinv);
  *(bf16x4*)(Ob + f) = o;
}

// ---------------- launch ----------------

extern "C" void kernel_launch(void* const* d_in, const int* in_sizes, int n_in,
                              void* d_out, int out_size, void* d_ws, size_t ws_size,
                              hipStream_t stream) {
  const float* x      = (const float*)d_in[0];
  const float* w_qkv  = (const float*)d_in[1];
  const float* temp   = (const float*)d_in[2];
  const float* w_out  = (const float*)d_in[3];
  const float* b_out  = (const float*)d_in[4];
  float* out          = (float*)d_out;

  char* ws = (char*)d_ws;
  bf16*  Xb    = (bf16*)(ws);                         // 8 MB
  bf16*  Wt    = (bf16*)(ws + (size_t)(8u  << 20));   // 1.5 MB
  bf16*  Qb    = (bf16*)(ws + (size_t)(10u << 20));   // 8 MB
  bf16*  Kb    = (bf16*)(ws + (size_t)(18u << 20));   // 8 MB
  bf16*  Vb    = (bf16*)(ws + (size_t)(26u << 20));   // 8 MB
  bf16*  Vtb   = (bf16*)(ws + (size_t)(34u << 20));   // 8 MB
  bf16*  Ob    = (bf16*)(ws + (size_t)(42u << 20));   // 8 MB
  bf16*  Wot   = (bf16*)(ws + (size_t)(50u << 20));   // 0.5 MB
  float* Lpart = (float*)(ws + (size_t)(51u << 20));  // 3 x 256 KB
  float* Opart = (float*)(ws + (size_t)(52u << 20));  // SPLIT x 16.78 MB

  // SPLIT=2, grid 32x16x2 = 1024 blocks = 4 blocks/CU x 256 CUs.
  const int split = (ws_size >= ((size_t)86u << 20)) ? 2 : 1;

  cast4_kernel<<<4096, 256, 0, stream>>>(x, Xb, (8192 * 512) / 4);
  wtrans_kernel<<<dim3(24, 8), 256, 0, stream>>>(w_qkv, Wt, 1536);
  wtrans_kernel<<<dim3(8, 8), 256, 0, stream>>>(w_out, Wot, 512);

  gemm_bt<0, 4><<<dim3(12, 64), 256, 0, stream>>>(Xb, Wt, Qb, Kb, Vb, nullptr, nullptr, temp);

  vtrans_kernel<<<dim3(64, 16), 256, 0, stream>>>(Vb, Vtb);

  if (split == 2) {
    attn_kernel<2><<<dim3(32, 16, 2), 256, 0, stream>>>(Qb, Kb, Vtb, nullptr, Opart, Lpart);
    merge_kernel<2><<<4096, 256, 0, stream>>>(Opart, Lpart, Ob);
  } else {
    attn_kernel<1><<<dim3(32, 16, 1), 256, 0, stream>>>(Qb, Kb, Vtb, Ob, nullptr, nullptr);
  }

  gemm_bt<1, 2><<<dim3(8, 64), 256, 0, stream>>>(Ob, Wot, nullptr, nullptr, nullptr, out, b_out, nullptr);
}

// Round 7
// 205.425 us; speedup vs baseline: 1.0705x; 1.0705x over previous
//
#include <hip/hip_runtime.h>

// LocalitySelfAttention: B=2, N=4096, DIM=512, H=8, d=64 (INNER=512)
// bf16 MFMA, fp32 accumulate. Head (b,h) = contiguous (4096x64) tile at
// offset (b*8+h)<<18 of the (8192x512) activation matrices (raw-reshape view).

typedef __bf16 bf16;
typedef __bf16 bf16x8 __attribute__((ext_vector_type(8)));
typedef __bf16 bf16x4 __attribute__((ext_vector_type(4)));
typedef __bf16 bf16x2 __attribute__((ext_vector_type(2)));
typedef float  f32x4  __attribute__((ext_vector_type(4)));
typedef float  f32x16 __attribute__((ext_vector_type(16)));
typedef unsigned u32x4 __attribute__((ext_vector_type(4)));

#define MFMA_BF16(a, b, c)   __builtin_amdgcn_mfma_f32_16x16x32_bf16((a), (b), (c), 0, 0, 0)
#define MFMA32_BF16(a, b, c) __builtin_amdgcn_mfma_f32_32x32x16_bf16((a), (b), (c), 0, 0, 0)

__device__ __forceinline__ void gld_lds16(void* lds, const void* g) {
  __builtin_amdgcn_global_load_lds(
      (const __attribute__((address_space(1))) void*)g,
      (__attribute__((address_space(3))) void*)lds, 16, 0, 0);
}

// pack two f32 -> one u32 of 2 bf16
__device__ __forceinline__ unsigned pkbf(float a, float b) {
  bf16x2 t; t[0] = (bf16)a; t[1] = (bf16)b;
  return __builtin_bit_cast(unsigned, t);
}

// ---------------- converters ----------------

__global__ void cast4_kernel(const float* __restrict__ in, bf16* __restrict__ out, int n4) {
  int i = blockIdx.x * 256 + threadIdx.x;
  if (i >= n4) return;
  float4 v = ((const float4*)in)[i];
  bf16x4 o;
  o[0] = (bf16)v.x; o[1] = (bf16)v.y; o[2] = (bf16)v.z; o[3] = (bf16)v.w;
  *(bf16x4*)(out + 4 * i) = o;
}

// out (C x 512) = in (512 x C)^T, f32 -> bf16, LDS-tiled
__global__ void wtrans_kernel(const float* __restrict__ in, bf16* __restrict__ out, int C) {
  __shared__ float tile[64 * 65];
  const int t = threadIdx.x;
  const int c0 = blockIdx.x * 64, r0 = blockIdx.y * 64;
#pragma unroll
  for (int p = 0; p < 16; p++) {
    int idx = p * 256 + t, r = idx >> 6, c = idx & 63;
    tile[r * 65 + c] = in[(r0 + r) * C + c0 + c];
  }
  __syncthreads();
#pragma unroll
  for (int p = 0; p < 16; p++) {
    int idx = p * 256 + t, c = idx >> 6, r = idx & 63;
    out[(size_t)(c0 + c) * 512 + r0 + r] = (bf16)tile[r * 65 + c];
  }
}

// per-head (4096x64) -> (64x4096), LDS-tiled. grid (64 n-tiles, 16 heads)
__global__ void vtrans_kernel(const bf16* __restrict__ V, bf16* __restrict__ Vt) {
  __shared__ bf16 tile[64 * 65];
  const int t = threadIdx.x;
  const size_t base = (size_t)blockIdx.y << 18;
  const int n0 = blockIdx.x * 64;
#pragma unroll
  for (int p = 0; p < 16; p++) {
    int idx = p * 256 + t, r = idx >> 6, c = idx & 63;
    tile[r * 65 + c] = V[base + (size_t)(n0 + r) * 64 + c];
  }
  __syncthreads();
#pragma unroll
  for (int p = 0; p < 16; p++) {
    int idx = p * 256 + t, d = idx >> 6, n = idx & 63;
    Vt[base + (size_t)d * 4096 + n0 + n] = tile[n * 65 + d];
  }
}

// ---------------- GEMM: C(M x *) = A(Mx512) * Bt(*x512)^T ----------------

template<int EPI, int WNT>
__global__ __launch_bounds__(256) void gemm_bt(
    const bf16* __restrict__ A, const bf16* __restrict__ Bt,
    bf16* __restrict__ oQ, bf16* __restrict__ oK, bf16* __restrict__ oV,
    float* __restrict__ oC, const float* __restrict__ bias,
    const float* __restrict__ temp)
{
  __shared__ bf16 As[128 * 32];
  __shared__ bf16 Bs[WNT * 32 * 32];

  const int t    = threadIdx.x;
  const int lane = t & 63;
  const int w    = t >> 6;
  const int mm   = lane & 15;
  const int q    = lane >> 4;
  const int wm   = w >> 1, wn = w & 1;
  const int m0   = blockIdx.y * 128;
  const int n0   = blockIdx.x * (WNT * 32);

  const int srow = t >> 2, sch = t & 3;
  const int gch  = sch ^ ((srow >> 1) & 3);
  const bf16* Ab = A  + (m0 + srow) * 512 + gch * 8;
  const bf16* Bb = Bt + (n0 + srow) * 512 + gch * 8;
  bf16* Asl = As + t * 8;
  bf16* Bsl = Bs + t * 8;

  const int fslot = (q ^ ((mm >> 1) & 3)) * 8;

  const f32x4 zero4 = {0.f, 0.f, 0.f, 0.f};
  f32x4 acc[4][WNT];
#pragma unroll
  for (int i = 0; i < 4; i++)
#pragma unroll
    for (int j = 0; j < WNT; j++) acc[i][j] = zero4;

  for (int k0 = 0; k0 < 512; k0 += 32) {
    __syncthreads();
    gld_lds16(Asl,        Ab + k0);
    gld_lds16(Asl + 2048, Ab + 64 * 512 + k0);
    gld_lds16(Bsl,        Bb + k0);
    if (WNT == 4) gld_lds16(Bsl + 2048, Bb + 64 * 512 + k0);
    __syncthreads();

    bf16x8 af[4], bfv[WNT];
#pragma unroll
    for (int i = 0; i < 4; i++)
      af[i] = *(const bf16x8*)(As + (wm * 64 + i * 16 + mm) * 32 + fslot);
#pragma unroll
    for (int j = 0; j < WNT; j++)
      bfv[j] = *(const bf16x8*)(Bs + (wn * (WNT * 16) + j * 16 + mm) * 32 + fslot);

#pragma unroll
    for (int i = 0; i < 4; i++)
#pragma unroll
      for (int j = 0; j < WNT; j++)
        acc[i][j] = MFMA_BF16(af[i], bfv[j], acc[i][j]);
  }

  if (EPI == 0) {
    // fold exp(temperature) AND log2(e) into Q so attention uses raw exp2
    const float scale = __expf(temp[0]) * 1.44269504088896f;
#pragma unroll
    for (int i = 0; i < 4; i++) {
      const int row = m0 + wm * 64 + i * 16 + q * 4;
#pragma unroll
      for (int j = 0; j < WNT; j++) {
        const int col = n0 + wn * (WNT * 16) + j * 16 + mm;
        bf16* dst; int c2; float s;
        if (col < 512)       { dst = oQ; c2 = col;        s = scale; }
        else if (col < 1024) { dst = oK; c2 = col - 512;  s = 1.0f;  }
        else                 { dst = oV; c2 = col - 1024; s = 1.0f;  }
#pragma unroll
        for (int r = 0; r < 4; r++)
          dst[(size_t)(row + r) * 512 + c2] = (bf16)(acc[i][j][r] * s);
      }
    }
  } else {
#pragma unroll
    for (int i = 0; i < 4; i++) {
      const int row = m0 + wm * 64 + i * 16 + q * 4;
#pragma unroll
      for (int j = 0; j < WNT; j++) {
        const int col = n0 + wn * (WNT * 16) + j * 16 + mm;
        const float b = bias[col];
#pragma unroll
        for (int r = 0; r < 4; r++)
          oC[(size_t)(row + r) * 512 + col] = acc[i][j][r] + b;
      }
    }
  }
}

// ---------------- flash attention v10: PV-deferred pipeline ----------------
// 4 waves x 32 Q-rows = 128-row block; KV tile 64; grid (32, 16); SPLIT=1
// (merge kernel deleted: TLP proven irrelevant in R4->R6, so the Opart f32
// round-trip bought nothing). QK as mfma_32x32x16(A=K, B=Q); P in registers.
//
// R6 findings: fence removal = null (regions weren't the limiter); kv
// rotation = 4x FETCH_SIZE regression (L2 locality) with no time gain ->
// reverted. The limiter is the per-iteration serial chain
// ds_read K -> QK -> exp2 -> pack -> PV (~1000 cyc, TLP only ~2x-covers).
// v10 breaks the chain: PV for tile it-1 runs at the TOP of iteration it,
// using only registers (pa + V-frags saved last iteration), inside the
// ds_read/QK shadow of tile it. exp->PV leaves the critical path.
// V-frags are (re)loaded into vfp AFTER the deferred PV consumed them.

__global__ __launch_bounds__(256, 2) void attn_kernel(
    const bf16* __restrict__ Q, const bf16* __restrict__ Kb,
    const bf16* __restrict__ Vt, bf16* __restrict__ O)
{
  __shared__ bf16 Ks[2][64 * 64];   // [buf][kv][d], chunk-swizzle key = kv&7
  __shared__ bf16 Vs[2][64 * 64];   // [buf][d][kv], chunk-swizzle key = d&7
  __shared__ float rsum[4][32];     // epilogue row sums

  const int t    = threadIdx.x;
  const int lane = t & 63;
  const int w    = t >> 6;
  const int c32  = lane & 31;
  const int h    = lane >> 5;
  const int pxa  = (lane ^ 32) << 2;   // ds_bpermute byte index of partner lane
  const int bh   = blockIdx.y;
  const int q0   = blockIdx.x * 128;
  const size_t hb = (size_t)bh << 18;
  const bf16* Qh = Q  + hb;
  const bf16* Kh = Kb + hb;
  const bf16* Vh = Vt + hb;
  const int q0w  = q0 + w * 32;     // this wave's first Q row (32-aligned)

  // Q B-frags (32x32x16): B[k][n], n = lane&31 = qrow, k = h*8+e per k-slot.
  bf16x8 qf[4];
#pragma unroll
  for (int s = 0; s < 4; s++)
    qf[s] = *(const bf16x8*)(Qh + (size_t)(q0w + c32) * 64 + s * 16 + h * 8);

  f32x16 o[2];              // o[dt]: C col = d (dt*32+c32), row = qrow via regs
#pragma unroll
  for (int dt = 0; dt < 2; dt++)
#pragma unroll
    for (int r = 0; r < 16; r++) o[dt][r] = 0.f;
  float lacc = 0.f;         // per-lane partial row sum, qrow = q0w + c32

  const int r0 = t >> 3, c0 = t & 7;
  const int g0 = c0 ^ (r0 & 7);
  const bf16* Kg = Kh + (size_t)r0 * 64 + g0 * 8;     // + kv*64 per tile
  const bf16* Vg = Vh + (size_t)r0 * 4096 + g0 * 8;   // + kv    per tile

  const int dtile  = q0w >> 6;        // kv tile index containing the diagonal
  const int kthalf = (q0w >> 5) & 1;  // which 32-half of that tile

  // loop-carried fragments: P A-frags and V B-frags of the PREVIOUS tile
  bf16x8 pap[2][2];         // [kt][s2]
  bf16x8 vfp[2][2][2];      // [kt][s2][dt]

  // prologue: stage tile 0 into buf 0
  {
    bf16* Kn = &Ks[0][t * 8];
    bf16* Vn = &Vs[0][t * 8];
    gld_lds16(Kn,        Kg);
    gld_lds16(Kn + 2048, Kg + (size_t)32 * 64);
    gld_lds16(Vn,        Vg);
    gld_lds16(Vn + 2048, Vg + (size_t)32 * 4096);
  }

  for (int it = 0; it < 64; it++) {
    const int cur = it & 1;
    // stage tile it+1 (wrapped; it=63 restages tile 0 harmlessly) into the
    // other buffer — its previous contents were last read in iter it-1,
    // which ended with a barrier.
    {
      const int kv = ((it + 1) & 63) * 64;
      bf16* Kn = &Ks[cur ^ 1][t * 8];
      bf16* Vn = &Vs[cur ^ 1][t * 8];
      gld_lds16(Kn,        Kg + (size_t)kv * 64);
      gld_lds16(Kn + 2048, Kg + (size_t)(kv + 32) * 64);
      gld_lds16(Vn,        Vg + kv);
      gld_lds16(Vn + 2048, Vg + (size_t)32 * 4096 + kv);
    }
    // counted wait: 4 just-issued stay in flight; tile it's 4 have landed.
    __asm__ volatile("s_waitcnt vmcnt(4)" ::: "memory");
    __builtin_amdgcn_s_barrier();
    __asm__ volatile("" ::: "memory");

    const bf16* Kc = Ks[cur];
    const bf16* Vc = Vs[cur];

    // ---- deferred PV for tile it-1: register-only, fills the ds_read/QK
    // shadow of tile it ----
    if (it) {
#pragma unroll
      for (int kt = 0; kt < 2; kt++)
#pragma unroll
        for (int s2 = 0; s2 < 2; s2++)
#pragma unroll
          for (int dt = 0; dt < 2; dt++)
            o[dt] = MFMA32_BF16(pap[kt][s2], vfp[kt][s2][dt], o[dt]);
    }

    // ---- QK for both kv halves ----
    f32x16 sv0, sv1;
#pragma unroll
    for (int r = 0; r < 16; r++) { sv0[r] = 0.f; sv1[r] = 0.f; }
    {
      bf16x8 kf[4];
#pragma unroll
      for (int s = 0; s < 4; s++)
        kf[s] = *(const bf16x8*)(Kc + c32 * 64 + (((s << 1) | h) ^ (c32 & 7)) * 8);
#pragma unroll
      for (int s = 0; s < 4; s++)
        sv0 = MFMA32_BF16(kf[s], qf[s], sv0);
    }
    {
      const int kr = 32 + c32;
      bf16x8 kf[4];
#pragma unroll
      for (int s = 0; s < 4; s++)
        kf[s] = *(const bf16x8*)(Kc + kr * 64 + (((s << 1) | h) ^ (kr & 7)) * 8);
#pragma unroll
      for (int s = 0; s < 4; s++)
        sv1 = MFMA32_BF16(kf[s], qf[s], sv1);
    }

    // ---- V B-frags for THIS tile -> vfp (old ones consumed by PV above) ----
#pragma unroll
    for (int kt = 0; kt < 2; kt++)
#pragma unroll
      for (int s2 = 0; s2 < 2; s2++)
#pragma unroll
        for (int dt = 0; dt < 2; dt++) {
          const int d = dt * 32 + c32;
          vfp[kt][s2][dt] =
              *(const bf16x8*)(Vc + d * 64 + (((((kt << 1) | s2) << 1) | h) ^ (d & 7)) * 8);
        }

    // ---- diagonal mask: one rare wave-uniform branch ----
    if (it == dtile) {
      if (kthalf == 0) {
#pragma unroll
        for (int r = 0; r < 16; r++)
          if (c32 == ((r & 3) + ((r >> 2) << 3) + (h << 2))) sv0[r] = -1e30f;
      } else {
#pragma unroll
        for (int r = 0; r < 16; r++)
          if (c32 == ((r & 3) + ((r >> 2) << 3) + (h << 2))) sv1[r] = -1e30f;
      }
    }

    // ---- exp2 + row-sum + pack -> pap (PV itself deferred to next iter) ----
#pragma unroll
    for (int kt = 0; kt < 2; kt++) {
      float pp[16];
#pragma unroll
      for (int r = 0; r < 16; r++)
        pp[r] = __builtin_amdgcn_exp2f(kt ? sv1[r] : sv0[r]);
      float s8[8];
#pragma unroll
      for (int r = 0; r < 8; r++) s8[r] = pp[r] + pp[r + 8];
      float s4[4];
#pragma unroll
      for (int r = 0; r < 4; r++) s4[r] = s8[r] + s8[r + 4];
      lacc += (s4[0] + s4[1]) + (s4[2] + s4[3]);

      // Lane (c32,h) holds kv {4h+0..3, 8+4h+0..3} per 16-step; A-frag word j
      // needs k = 8h + {2j,2j+1}; the other half's words come from lane^32.
#pragma unroll
      for (int s2 = 0; s2 < 2; s2++) {
        const int b = s2 * 8;
        unsigned wa = pkbf(pp[b + 0], pp[b + 1]);
        unsigned wc = pkbf(pp[b + 2], pp[b + 3]);
        unsigned wb = pkbf(pp[b + 4], pp[b + 5]);
        unsigned wd = pkbf(pp[b + 6], pp[b + 7]);
        unsigned r1 = (unsigned)__builtin_amdgcn_ds_bpermute(pxa, (int)(h ? wa : wb));
        unsigned r2 = (unsigned)__builtin_amdgcn_ds_bpermute(pxa, (int)(h ? wc : wd));
        u32x4 wv;
        wv[0] = h ? r1 : wa;
        wv[1] = h ? r2 : wc;
        wv[2] = h ? wb : r1;
        wv[3] = h ? wd : r2;
        pap[kt][s2] = __builtin_bit_cast(bf16x8, wv);
      }
    }

    __asm__ volatile("" ::: "memory");
    __builtin_amdgcn_s_barrier();   // all waves done reading buf[cur]
  }

  // ---- final deferred PV (tile 63) ----
#pragma unroll
  for (int kt = 0; kt < 2; kt++)
#pragma unroll
    for (int s2 = 0; s2 < 2; s2++)
#pragma unroll
      for (int dt = 0; dt < 2; dt++)
        o[dt] = MFMA32_BF16(pap[kt][s2], vfp[kt][s2][dt], o[dt]);

  // combine per-lane partial row sums across lane halves (kv coverage is
  // complementary between lane l and l^32; qrow identical)
  const int pb = __builtin_amdgcn_ds_bpermute(pxa, __builtin_bit_cast(int, lacc));
  const float tot = lacc + __builtin_bit_cast(float, pb);

  bf16* Oh = O + hb;
  if (h == 0) rsum[w][c32] = tot;
  __asm__ volatile("s_waitcnt lgkmcnt(0)" ::: "memory");
#pragma unroll
  for (int r = 0; r < 16; r++) {
    const int row = (r & 3) + ((r >> 2) << 3) + (h << 2);
    const float rinv = 1.0f / rsum[w][row];
#pragma unroll
    for (int dt = 0; dt < 2; dt++)
      Oh[(size_t)(q0w + row) * 64 + dt * 32 + c32] = (bf16)(o[dt][r] * rinv);
  }
}

// ---------------- launch ----------------

extern "C" void kernel_launch(void* const* d_in, const int* in_sizes, int n_in,
                              void* d_out, int out_size, void* d_ws, size_t ws_size,
                              hipStream_t stream) {
  const float* x      = (const float*)d_in[0];
  const float* w_qkv  = (const float*)d_in[1];
  const float* temp   = (const float*)d_in[2];
  const float* w_out  = (const float*)d_in[3];
  const float* b_out  = (const float*)d_in[4];
  float* out          = (float*)d_out;

  char* ws = (char*)d_ws;
  bf16*  Xb    = (bf16*)(ws);                         // 8 MB
  bf16*  Wt    = (bf16*)(ws + (size_t)(8u  << 20));   // 1.5 MB
  bf16*  Qb    = (bf16*)(ws + (size_t)(10u << 20));   // 8 MB
  bf16*  Kb    = (bf16*)(ws + (size_t)(18u << 20));   // 8 MB
  bf16*  Vb    = (bf16*)(ws + (size_t)(26u << 20));   // 8 MB
  bf16*  Vtb   = (bf16*)(ws + (size_t)(34u << 20));   // 8 MB
  bf16*  Ob    = (bf16*)(ws + (size_t)(42u << 20));   // 8 MB
  bf16*  Wot   = (bf16*)(ws + (size_t)(50u << 20));   // 0.5 MB

  cast4_kernel<<<4096, 256, 0, stream>>>(x, Xb, (8192 * 512) / 4);
  wtrans_kernel<<<dim3(24, 8), 256, 0, stream>>>(w_qkv, Wt, 1536);
  wtrans_kernel<<<dim3(8, 8), 256, 0, stream>>>(w_out, Wot, 512);

  gemm_bt<0, 4><<<dim3(12, 64), 256, 0, stream>>>(Xb, Wt, Qb, Kb, Vb, nullptr, nullptr, temp);

  vtrans_kernel<<<dim3(64, 16), 256, 0, stream>>>(Vb, Vtb);

  attn_kernel<<<dim3(32, 16), 256, 0, stream>>>(Qb, Kb, Vtb, Ob);

  gemm_bt<1, 2><<<dim3(8, 64), 256, 0, stream>>>(Ob, Wot, nullptr, nullptr, nullptr, out, b_out, nullptr);
}